// Round 4
// baseline (130.293 us; speedup 1.0000x reference)
//
#include <hip/hip_runtime.h>
#include <hip/hip_bf16.h>
#include <stdint.h>

#define NASSETS 512
#define WINDOW  256
#define NBATCH  32
#define NWORDS  16      // 512 bits / 32
#define XSTRIDE 80      // LDS slab row stride (64 data bytes + 16 pad), 16B-aligned

typedef __attribute__((ext_vector_type(4))) float floatx4;
typedef __attribute__((ext_vector_type(4))) int   intx4;
typedef __attribute__((ext_vector_type(2))) long  longx2;

// ---- fp32 -> OCP e4m3fn helpers ----
__device__ __forceinline__ unsigned int f2e4m3_manual(float x) {
    union { float f; unsigned u; } c; c.f = x;
    unsigned s = (c.u >> 24) & 0x80u;
    unsigned a = c.u & 0x7FFFFFFFu;
    float af = fabsf(x);
    unsigned code;
    if (af >= 448.f) code = 0x7Eu;                 // saturate to max finite
    else if (af < 0.015625f) {                     // subnormal range, step 2^-9
        code = (unsigned)(int)rintf(af * 512.f);   // 0..8 (8 == 2^-6 normal)
    } else {
        unsigned E = a >> 23;                      // 121..135
        unsigned base = ((E - 120u) << 3) | ((a >> 20) & 7u);
        unsigned rem = a & 0xFFFFFu;
        if (rem > 0x80000u || (rem == 0x80000u && (base & 1u))) base++;
        if (base > 0x7Eu) base = 0x7Eu;
        code = base;
    }
    return s | code;
}

__device__ __forceinline__ int pack4fp8(float f0, float f1, float f2, float f3) {
#if defined(__has_builtin) && __has_builtin(__builtin_amdgcn_cvt_pk_fp8_f32)
    int v = 0;
    v = __builtin_amdgcn_cvt_pk_fp8_f32(f0, f1, v, false);  // bytes 0,1
    v = __builtin_amdgcn_cvt_pk_fp8_f32(f2, f3, v, true);   // bytes 2,3
    return v;
#else
    return (int)(f2e4m3_manual(f0) | (f2e4m3_manual(f1) << 8) |
                 (f2e4m3_manual(f2) << 16) | (f2e4m3_manual(f3) << 24));
#endif
}

// Kernel 1: fused single-read normalize + transpose, fp8 output Xt[b][n][w] (1 B/elem).
// grid (8 asset-groups, 32 batches), block 512. Thread (a=t&63, wc=t>>6) holds 32
// floats of column n0+a in registers; fp32 stats via LDS reduce; fp8 pack ->
// XOR-swizzled LDS tile -> coalesced transposed writeout.
__global__ __launch_bounds__(512)
void normalize_kernel(const float* __restrict__ ret, char* __restrict__ Xt) {
    __shared__ float sred[512];
    __shared__ float ssred[512];
    __shared__ float smean[64];
    __shared__ float sinv[64];
    __shared__ __align__(16) char tile[64 * 256];  // 16 KB; row a: 16 segs of 16B, seg s at s^(a&15)

    const int t  = threadIdx.x;
    const int a  = t & 63;
    const int wc = t >> 6;                 // 0..7, 32 w's each
    const int g  = blockIdx.x;
    const int b  = blockIdx.y;
    const int n0 = g * 64;

    const float* base = ret + (size_t)b * WINDOW * NASSETS + n0 + a;

    float x[32];
    float s1 = 0.f, s2 = 0.f;
#pragma unroll
    for (int k = 0; k < 32; ++k) {
        x[k] = base[(size_t)(wc * 32 + k) * NASSETS];
        s1 += x[k];
        s2 += x[k] * x[k];
    }
    sred[wc * 64 + a]  = s1;
    ssred[wc * 64 + a] = s2;
    __syncthreads();

    if (t < 64) {
        float S = 0.f, S2 = 0.f;
#pragma unroll
        for (int c = 0; c < 8; ++c) { S += sred[c * 64 + t]; S2 += ssred[c * 64 + t]; }
        float mean = S / (float)WINDOW;
        float var  = (S2 - (float)WINDOW * mean * mean) / (float)(WINDOW - 1);
        if (var < 0.f) var = 0.f;
        float stdv = sqrtf(var) + 1e-8f;   // matches ref: std(ddof=1) + 1e-8
        smean[t] = mean;
        sinv[t]  = 1.0f / stdv;
    }
    __syncthreads();

    const float mn = smean[a];
    const float iv = sinv[a];

    int pk[8];
#pragma unroll
    for (int j = 0; j < 8; ++j)
        pk[j] = pack4fp8((x[4*j+0] - mn) * iv, (x[4*j+1] - mn) * iv,
                         (x[4*j+2] - mn) * iv, (x[4*j+3] - mn) * iv);
    char* rowp = tile + a * 256;
    intx4 lo = {pk[0], pk[1], pk[2], pk[3]};
    intx4 hi = {pk[4], pk[5], pk[6], pk[7]};
    *(intx4*)(rowp + ((wc * 2 + 0) ^ (a & 15)) * 16) = lo;
    *(intx4*)(rowp + ((wc * 2 + 1) ^ (a & 15)) * 16) = hi;
    __syncthreads();

    // writeout: 1024 16B segs; wave covers 4 rows x 16 segs = 1 KB contiguous
    char* orow = Xt + ((size_t)b * NASSETS + n0) * WINDOW;
#pragma unroll
    for (int it = 0; it < 2; ++it) {
        int idx = it * 512 + t;
        int r = idx >> 4;
        int s = idx & 15;
        intx4 v = *(const intx4*)(tile + r * 256 + (s ^ (r & 15)) * 16);
        *(intx4*)(orow + r * WINDOW + s * 16) = v;
    }
}

// Kernel 2: FUSED corr (fp8 MFMA) + threshold bit-pack + connected components.
// grid 32 (one block per batch), block 512 = 8 waves; wave w owns rows [w*64, w*64+64).
// K-slab staged in LDS (512 rows x 64 fp8-k, 40 KB); j-strips of 128 cols;
// adjacency words spilled to global scratch between MFMA and CC phases.
__global__ __launch_bounds__(512)
void fused_corr_cc_kernel(const char* __restrict__ Xt, unsigned int* __restrict__ adjG,
                          float* __restrict__ out) {
    __shared__ __align__(16) char Xs[NASSETS * XSTRIDE];   // 40 KB
    __shared__ int lab[NASSETS];
    __shared__ int red[8];
    __shared__ int changed;

    const int t    = threadIdx.x;
    const int lane = t & 63;
    const int wave = t >> 6;
    const int b    = blockIdx.x;
    const int R0   = wave * 64;

    const int m  = lane & 15;
    const int kq = lane >> 4;     // k-quad

    const float T[3] = {0.3f * (float)WINDOW, 0.5f * (float)WINDOW, 0.7f * (float)WINDOW};
    const char* xbase = Xt + ((size_t)b * NASSETS) * WINDOW;

    for (int j0 = 0; j0 < NASSETS; j0 += 128) {
        floatx4 acc[4][8] = {};

        for (int k0 = 0; k0 < WINDOW; k0 += 64) {
            __syncthreads();   // prior slab's frag reads complete
            // stage slab: 512 rows x 64 bytes; layout row n: seg q at (q^(n&3))*16,
            // byte (q,h,j) at seg_off + h*8 + j  (h = k-step parity, j = byte in frag)
#pragma unroll
            for (int it = 0; it < 4; ++it) {
                int idx = it * 512 + t;            // 0..2047
                int n   = idx >> 2;
                int c   = idx & 3;                 // 16B chunk within slab row
                longx2 v = *(const longx2*)(xbase + (size_t)n * WINDOW + k0 + c * 16);
                int q0 = (2 * c) & 3, q1 = (2 * c + 1) & 3;
                int h  = (c >> 1) & 1;
                char* rp = Xs + n * XSTRIDE;
                *(long*)(rp + ((q0 ^ (n & 3)) * 16) + h * 8) = v.x;
                *(long*)(rp + ((q1 ^ (n & 3)) * 16) + h * 8) = v.y;
            }
            __syncthreads();

            longx2 af[4], bf[8];
#pragma unroll
            for (int mi = 0; mi < 4; ++mi) {
                int n = R0 + mi * 16 + m;
                af[mi] = *(const longx2*)(Xs + n * XSTRIDE + ((kq ^ (n & 3)) * 16));
            }
#pragma unroll
            for (int nj = 0; nj < 8; ++nj) {
                int n = j0 + nj * 16 + m;
                bf[nj] = *(const longx2*)(Xs + n * XSTRIDE + ((kq ^ (n & 3)) * 16));
            }
#pragma unroll
            for (int mi = 0; mi < 4; ++mi)
#pragma unroll
                for (int nj = 0; nj < 8; ++nj) {
                    acc[mi][nj] = __builtin_amdgcn_mfma_f32_16x16x32_fp8_fp8(
                        af[mi].x, bf[nj].x, acc[mi][nj], 0, 0, 0);
                    acc[mi][nj] = __builtin_amdgcn_mfma_f32_16x16x32_fp8_fp8(
                        af[mi].y, bf[nj].y, acc[mi][nj], 0, 0, 0);
                }
        }

        // ballot bit-pack: C/D layout col=lane&15, row=(lane>>4)*4+r (validated).
        // Lane L owns wave-local row L: mi=L>>4, qp=(L>>2)&3, r=L&3.
        unsigned int wrd[3][4];
        const int myMi = lane >> 4, myQp = (lane >> 2) & 3, myR = lane & 3;
#pragma unroll
        for (int mi = 0; mi < 4; ++mi)
#pragma unroll
            for (int r = 0; r < 4; ++r) {
                bool act = (myMi == mi) && (myR == r);
#pragma unroll
                for (int th = 0; th < 3; ++th)
#pragma unroll
                    for (int jw = 0; jw < 4; ++jw) {
                        unsigned long long blo = __ballot(fabsf(acc[mi][2*jw][r])   > T[th]);
                        unsigned long long bhi = __ballot(fabsf(acc[mi][2*jw+1][r]) > T[th]);
                        if (act)
                            wrd[th][jw] = ((unsigned)(blo >> (myQp * 16)) & 0xFFFFu)
                                        | (((unsigned)(bhi >> (myQp * 16)) & 0xFFFFu) << 16);
                    }
            }

        const int grow = R0 + lane;        // row within batch (= tid)
        int dd = grow - j0;
        if (dd >= 0 && dd < 128) {         // zero diagonal bit
            unsigned mask = ~(1u << (dd & 31));
            int w = dd >> 5;
#pragma unroll
            for (int th = 0; th < 3; ++th) wrd[th][w] &= mask;
        }
#pragma unroll
        for (int th = 0; th < 3; ++th) {
            size_t rbase = ((size_t)(th * NBATCH + b) * NASSETS + grow) * NWORDS + (j0 >> 5);
#pragma unroll
            for (int jw = 0; jw < 4; ++jw) adjG[rbase + jw] = wrd[th][jw];
        }
    }

    // ---- CC phase: 3 thresholds sequentially ----
    const int lane6 = t & 63, wv = t >> 6;
    for (int th = 0; th < 3; ++th) {
        __syncthreads();   // adjG writes visible (within-block) / prior th done
        const unsigned int* rowp = adjG + ((size_t)(th * NBATCH + b) * NASSETS + t) * NWORDS;
        unsigned int row[NWORDS];
        int deg = 0;
#pragma unroll
        for (int w = 0; w < NWORDS; ++w) {
            row[w] = rowp[w];
            deg += __popc(row[w]);
        }
        int v = deg;
#pragma unroll
        for (int off = 32; off > 0; off >>= 1) v += __shfl_down(v, off);
        if (lane6 == 0) red[wv] = v;
        lab[t] = t;
        __syncthreads();
        int total_deg = 0;
        if (t == 0)
            for (int k = 0; k < 8; ++k) total_deg += red[k];

        // min-label propagation + pointer jumping (monotone -> terminates)
        for (;;) {
            __syncthreads();
            if (t == 0) changed = 0;
            __syncthreads();
            int mlab = lab[t];
#pragma unroll
            for (int w = 0; w < NWORDS; ++w) {
                unsigned int bits = row[w];
                int basej = w * 32;
                while (bits) {
                    int j = basej + __builtin_ctz(bits);
                    bits &= bits - 1;
                    int lj = lab[j];
                    if (lj < mlab) mlab = lj;
                }
            }
            int lm = lab[mlab];
            if (lm < mlab) mlab = lm;
            __syncthreads();
            if (mlab < lab[t]) { lab[t] = mlab; changed = 1; }
            __syncthreads();
            if (!changed) break;
        }

        int isrep = (lab[t] == t) ? 1 : 0;
#pragma unroll
        for (int off = 32; off > 0; off >>= 1) isrep += __shfl_down(isrep, off);
        __syncthreads();   // protect red[] reuse
        if (lane6 == 0) red[wv] = isrep;
        __syncthreads();
        if (t == 0) {
            int comps = 0;
            for (int k = 0; k < 8; ++k) comps += red[k];
            float compf = (float)comps;
            float edges = (float)total_deg * 0.5f;
            out[b * 6 + th * 2 + 0] = compf / (float)NASSETS;
            out[b * 6 + th * 2 + 1] = fmaxf(0.0f, edges - (float)NASSETS + compf) / (float)NASSETS;
        }
    }
}

extern "C" void kernel_launch(void* const* d_in, const int* in_sizes, int n_in,
                              void* d_out, int out_size, void* d_ws, size_t ws_size,
                              hipStream_t stream) {
    const float* ret = (const float*)d_in[0];
    float* out = (float*)d_out;
    char* ws = (char*)d_ws;

    char* Xt = ws;                                                    // 4 MB fp8
    unsigned int* adjG =
        (unsigned int*)(ws + (size_t)NBATCH * NASSETS * WINDOW);      // 3 MB

    dim3 g1(NASSETS / 64, NBATCH);
    normalize_kernel<<<g1, 512, 0, stream>>>(ret, Xt);

    fused_corr_cc_kernel<<<NBATCH, 512, 0, stream>>>(Xt, adjG, out);
}

// Round 5
// 78.451 us; speedup vs baseline: 1.6608x; 1.6608x over previous
//
#include <hip/hip_runtime.h>
#include <hip/hip_bf16.h>
#include <stdint.h>

#define NASSETS 512
#define WINDOW  256
#define NBATCH  32
#define NWORDS  16      // 512 bits / 32
#define BM 128
#define BN 128

typedef __attribute__((ext_vector_type(4))) float floatx4;
typedef __attribute__((ext_vector_type(4))) int   intx4;
typedef __attribute__((ext_vector_type(2))) long  longx2;

// ---- fp32 -> OCP e4m3fn (validated R4: absmax=0) ----
__device__ __forceinline__ unsigned int f2e4m3_manual(float x) {
    union { float f; unsigned u; } c; c.f = x;
    unsigned s = (c.u >> 24) & 0x80u;
    unsigned a = c.u & 0x7FFFFFFFu;
    float af = fabsf(x);
    unsigned code;
    if (af >= 448.f) code = 0x7Eu;
    else if (af < 0.015625f) {
        code = (unsigned)(int)rintf(af * 512.f);
    } else {
        unsigned E = a >> 23;
        unsigned base = ((E - 120u) << 3) | ((a >> 20) & 7u);
        unsigned rem = a & 0xFFFFFu;
        if (rem > 0x80000u || (rem == 0x80000u && (base & 1u))) base++;
        if (base > 0x7Eu) base = 0x7Eu;
        code = base;
    }
    return s | code;
}

__device__ __forceinline__ int pack4fp8(float f0, float f1, float f2, float f3) {
#if defined(__has_builtin) && __has_builtin(__builtin_amdgcn_cvt_pk_fp8_f32)
    int v = 0;
    v = __builtin_amdgcn_cvt_pk_fp8_f32(f0, f1, v, false);
    v = __builtin_amdgcn_cvt_pk_fp8_f32(f2, f3, v, true);
    return v;
#else
    return (int)(f2e4m3_manual(f0) | (f2e4m3_manual(f1) << 8) |
                 (f2e4m3_manual(f2) << 16) | (f2e4m3_manual(f3) << 24));
#endif
}

// async global->LDS, 16B/lane; LDS dst is wave-uniform base + lane*16;
// GLOBAL addr is per-lane.
__device__ __forceinline__ void gload16(const void* gp, void* lp) {
    __builtin_amdgcn_global_load_lds(
        (const __attribute__((address_space(1))) void*)(uintptr_t)gp,
        (__attribute__((address_space(3))) void*)(unsigned int)(uintptr_t)lp,
        16, 0, 0);
}

// Kernel 1: fused single-read normalize + transpose -> fp8 Xt[b][n][256B row].
// Row layout: 4 slabs of 64 k; slab slot q (16B) = k[q*8..+7] ++ k[32+q*8..+7]
// (pre-interleaved so corr's ds_read_b128 yields both K=32 frags directly).
// grid (8 asset-groups, 32 batches), block 512; thread (a=t&63, wc=t>>6).
__global__ __launch_bounds__(512)
void normalize_kernel(const float* __restrict__ ret, char* __restrict__ Xt) {
    __shared__ float sred[512];
    __shared__ float ssred[512];
    __shared__ float smean[64];
    __shared__ float sinv[64];
    __shared__ __align__(16) char tile[64 * 256];  // 16 KB; row a: 16 slots, slot L at L^(a&15)

    const int t  = threadIdx.x;
    const int a  = t & 63;
    const int wc = t >> 6;                 // 0..7, 32 w's each
    const int g  = blockIdx.x;
    const int b  = blockIdx.y;
    const int n0 = g * 64;

    const float* base = ret + (size_t)b * WINDOW * NASSETS + n0 + a;

    float x[32];
    float s1 = 0.f, s2 = 0.f;
#pragma unroll
    for (int k = 0; k < 32; ++k) {
        x[k] = base[(size_t)(wc * 32 + k) * NASSETS];
        s1 += x[k];
        s2 += x[k] * x[k];
    }
    sred[wc * 64 + a]  = s1;
    ssred[wc * 64 + a] = s2;
    __syncthreads();

    if (t < 64) {
        float S = 0.f, S2 = 0.f;
#pragma unroll
        for (int c = 0; c < 8; ++c) { S += sred[c * 64 + t]; S2 += ssred[c * 64 + t]; }
        float mean = S / (float)WINDOW;
        float var  = (S2 - (float)WINDOW * mean * mean) / (float)(WINDOW - 1);
        if (var < 0.f) var = 0.f;
        float stdv = sqrtf(var) + 1e-8f;   // ref: std(ddof=1) + 1e-8
        smean[t] = mean;
        sinv[t]  = 1.0f / stdv;
    }
    __syncthreads();

    const float mn = smean[a];
    const float iv = sinv[a];

    int pk[8];
#pragma unroll
    for (int j = 0; j < 8; ++j)
        pk[j] = pack4fp8((x[4*j+0] - mn) * iv, (x[4*j+1] - mn) * iv,
                         (x[4*j+2] - mn) * iv, (x[4*j+3] - mn) * iv);

    // thread covers slab s = wc>>1, half h = wc&1; piece q -> slot L=s*4+q, byte h*8
    char* rowp = tile + a * 256;
    const int s  = wc >> 1;
    const int h8 = (wc & 1) * 8;
#pragma unroll
    for (int q = 0; q < 4; ++q) {
        unsigned long long piece = (unsigned)pk[2*q] |
                                   ((unsigned long long)(unsigned)pk[2*q+1] << 32);
        int L = s * 4 + q;
        *(unsigned long long*)(rowp + ((L ^ (a & 15)) * 16) + h8) = piece;
    }
    __syncthreads();

    // writeout: 1024 16B segs; logical slot order = interleaved row layout
    char* orow = Xt + ((size_t)b * NASSETS + n0) * WINDOW;
#pragma unroll
    for (int it = 0; it < 2; ++it) {
        int idx = it * 512 + t;
        int r = idx >> 4;
        int sl = idx & 15;
        intx4 v = *(const intx4*)(tile + r * 256 + ((sl ^ (r & 15)) * 16));
        *(intx4*)(orow + r * WINDOW + sl * 16) = v;
    }
}

// Kernel 2: 128x128 corr tile, fp8 MFMA, gload16 staging, ballot bit-pack.
// grid (4 jt, 4 it, 32 b) = 512 blocks, block 256 = 4 waves (2x2, 64x64 each).
// LDS rows 64 B (one slab), physical 16B slot p of row r holds global slot p^(r&3).
__global__ __launch_bounds__(256)
void corr_adj_kernel(const char* __restrict__ Xt, unsigned int* __restrict__ adj) {
    __shared__ __align__(16) char lsA[BM * 64];   // 8 KB
    __shared__ __align__(16) char lsB[BN * 64];   // 8 KB

    const int t    = threadIdx.x;
    const int lane = t & 63;
    const int wave = t >> 6;
    const int wi   = wave >> 1, wj = wave & 1;
    const int b  = blockIdx.z;
    const int i0 = blockIdx.y * BM;
    const int j0 = blockIdx.x * BN;

    const char* base = Xt + (size_t)b * NASSETS * WINDOW;

    const int m  = lane & 15;
    const int kq = lane >> 4;

    // staging: one instr = 16 rows x 64 B; lane l -> row +(l>>2), phys slot l&3,
    // global slot (l&3)^((l>>2)&3)  [row&3 == (l>>2)&3 since chunk row0 % 16 == 0]
    const int srowAdd  = lane >> 2;
    const int gslotOff = ((lane & 3) ^ ((lane >> 2) & 3)) * 16;

    floatx4 acc[4][4] = {};

    for (int k0 = 0; k0 < WINDOW; k0 += 64) {
        __syncthreads();   // prior iteration's frag reads complete
#pragma unroll
        for (int c = 0; c < 2; ++c) {
            int r0 = (wave * 2 + c) * 16;
            const char* gA = base + (size_t)(i0 + r0 + srowAdd) * WINDOW + k0 + gslotOff;
            const char* gB = base + (size_t)(j0 + r0 + srowAdd) * WINDOW + k0 + gslotOff;
            gload16(gA, (char*)lsA + r0 * 64);
            gload16(gB, (char*)lsB + r0 * 64);
        }
        __syncthreads();   // vmcnt drained -> staged data visible

        longx2 af[4], bf[4];
#pragma unroll
        for (int mi = 0; mi < 4; ++mi) {
            int r = wi * 64 + mi * 16 + m;
            af[mi] = *(const longx2*)(lsA + r * 64 + ((kq ^ (r & 3)) * 16));
        }
#pragma unroll
        for (int nj = 0; nj < 4; ++nj) {
            int r = wj * 64 + nj * 16 + m;
            bf[nj] = *(const longx2*)(lsB + r * 64 + ((kq ^ (r & 3)) * 16));
        }
#pragma unroll
        for (int mi = 0; mi < 4; ++mi)
#pragma unroll
            for (int nj = 0; nj < 4; ++nj) {
                acc[mi][nj] = __builtin_amdgcn_mfma_f32_16x16x32_fp8_fp8(
                    af[mi].x, bf[nj].x, acc[mi][nj], 0, 0, 0);
                acc[mi][nj] = __builtin_amdgcn_mfma_f32_16x16x32_fp8_fp8(
                    af[mi].y, bf[nj].y, acc[mi][nj], 0, 0, 0);
            }
    }

    // Ballot bit-pack epilogue (validated R2-R4). C/D: col=lane&15, row=(lane>>4)*4+r.
    const float T[3] = {0.3f * (float)WINDOW, 0.5f * (float)WINDOW, 0.7f * (float)WINDOW};
    unsigned int wout[3][2] = {{0u,0u},{0u,0u},{0u,0u}};
    const int qp = (lane >> 2) & 3;
#pragma unroll
    for (int mi = 0; mi < 4; ++mi) {
#pragma unroll
        for (int r = 0; r < 4; ++r) {
            bool act = ((lane >> 4) == mi) && ((lane & 3) == r);
#pragma unroll
            for (int th = 0; th < 3; ++th) {
                unsigned long long b0 = __ballot(fabsf(acc[mi][0][r]) > T[th]);
                unsigned long long b1 = __ballot(fabsf(acc[mi][1][r]) > T[th]);
                unsigned long long b2 = __ballot(fabsf(acc[mi][2][r]) > T[th]);
                unsigned long long b3 = __ballot(fabsf(acc[mi][3][r]) > T[th]);
                if (act) {
                    wout[th][0] = ((unsigned)(b0 >> (qp * 16)) & 0xFFFFu)
                                | (((unsigned)(b1 >> (qp * 16)) & 0xFFFFu) << 16);
                    wout[th][1] = ((unsigned)(b2 >> (qp * 16)) & 0xFFFFu)
                                | (((unsigned)(b3 >> (qp * 16)) & 0xFFFFu) << 16);
                }
            }
        }
    }

    const int grow    = i0 + wi * 64 + lane;
    const int colbase = j0 + wj * 64;
    unsigned int dd = (unsigned int)(grow - colbase);
    if (dd < 64u) {
        unsigned int m0 = (dd < 32u) ? ~(1u << dd) : 0xFFFFFFFFu;
        unsigned int m1 = (dd >= 32u) ? ~(1u << (dd - 32u)) : 0xFFFFFFFFu;
#pragma unroll
        for (int th = 0; th < 3; ++th) { wout[th][0] &= m0; wout[th][1] &= m1; }
    }
    const int wb = colbase >> 5;
    const size_t stride_t = (size_t)NBATCH * NASSETS * NWORDS;
    size_t rb = ((size_t)b * NASSETS + grow) * NWORDS + wb;
#pragma unroll
    for (int th = 0; th < 3; ++th) {
        adj[rb + th * stride_t]     = wout[th][0];
        adj[rb + th * stride_t + 1] = wout[th][1];
    }
}

// Kernel 3: connected components (min-label + pointer jumping) + edges. grid (3, 32).
__global__ __launch_bounds__(512)
void betti_kernel(const unsigned int* __restrict__ adj, float* __restrict__ out) {
    __shared__ int lab[NASSETS];
    __shared__ int changed;
    __shared__ int red[8];

    int th = blockIdx.x;
    int b  = blockIdx.y;
    int i  = threadIdx.x;
    int lane = i & 63, wv = i >> 6;

    const unsigned int* rowp =
        adj + (((size_t)th * NBATCH + b) * NASSETS + i) * NWORDS;
    unsigned int row[NWORDS];
    int deg = 0;
#pragma unroll
    for (int w = 0; w < NWORDS; ++w) {
        row[w] = rowp[w];
        deg += __popc(row[w]);
    }

    int v = deg;
#pragma unroll
    for (int off = 32; off > 0; off >>= 1) v += __shfl_down(v, off);
    if (lane == 0) red[wv] = v;
    lab[i] = i;
    __syncthreads();
    int total_deg = 0;
    if (i == 0)
        for (int k = 0; k < 8; ++k) total_deg += red[k];

    for (;;) {
        __syncthreads();
        if (i == 0) changed = 0;
        __syncthreads();
        int mlab = lab[i];
#pragma unroll
        for (int w = 0; w < NWORDS; ++w) {
            unsigned int bits = row[w];
            int basej = w * 32;
            while (bits) {
                int j = basej + __builtin_ctz(bits);
                bits &= bits - 1;
                int lj = lab[j];
                if (lj < mlab) mlab = lj;
            }
        }
        int lm = lab[mlab];
        if (lm < mlab) mlab = lm;
        __syncthreads();
        if (mlab < lab[i]) { lab[i] = mlab; changed = 1; }
        __syncthreads();
        if (!changed) break;
    }

    int isrep = (lab[i] == i) ? 1 : 0;
#pragma unroll
    for (int off = 32; off > 0; off >>= 1) isrep += __shfl_down(isrep, off);
    if (lane == 0) red[wv] = isrep;
    __syncthreads();
    if (i == 0) {
        int comps = 0;
        for (int k = 0; k < 8; ++k) comps += red[k];
        float compf = (float)comps;
        float edges = (float)total_deg * 0.5f;
        out[b * 6 + th * 2 + 0] = compf / (float)NASSETS;
        out[b * 6 + th * 2 + 1] = fmaxf(0.0f, edges - (float)NASSETS + compf) / (float)NASSETS;
    }
}

extern "C" void kernel_launch(void* const* d_in, const int* in_sizes, int n_in,
                              void* d_out, int out_size, void* d_ws, size_t ws_size,
                              hipStream_t stream) {
    const float* ret = (const float*)d_in[0];
    float* out = (float*)d_out;
    char* ws = (char*)d_ws;

    char* Xt = ws;                                                    // 4 MB fp8
    unsigned int* adj =
        (unsigned int*)(ws + (size_t)NBATCH * NASSETS * WINDOW);      // 3 MB

    dim3 g1(NASSETS / 64, NBATCH);
    normalize_kernel<<<g1, 512, 0, stream>>>(ret, Xt);

    dim3 g2(NASSETS / BN, NASSETS / BM, NBATCH);
    corr_adj_kernel<<<g2, 256, 0, stream>>>(Xt, adj);

    dim3 g3(3, NBATCH);
    betti_kernel<<<g3, 512, 0, stream>>>(adj, out);
}